// Round 1
// baseline (18325.627 us; speedup 1.0000x reference)
//
#include <hip/hip_runtime.h>
#include <hip/hip_bf16.h>
#include <math.h>

#define EMBED  512
#define HIDDEN 512
#define NGATE  2048          // 4*HIDDEN
#define OUTF   100
#define BATCH  500
#define TSTEPS 256

// ---------------------------------------------------------------------------
// Kernel 1: gates[b, g] = b_ih[g] + b_hh[g]
//                       + sum_e x_t[b,e] * W_ih[g,e] + sum_k h[b,k] * W_hh[g,k]
// Treated as one GEMM with K = 1024 (first 512 from x/W_ih, second 512 from
// h/W_hh). Both operands are K-contiguous row-major (C = A * W^T shape).
// Tile: 64(M) x 64(N), BK=16, 256 threads, 4x4 outputs/thread,
// register-prefetch to hide global latency under the 16-k compute.
// ---------------------------------------------------------------------------
__global__ __launch_bounds__(256) void gates_gemm(
    const float* __restrict__ x,     // inp_emb (BATCH, TSTEPS*EMBED)
    const float* __restrict__ h,     // (BATCH, HIDDEN)
    const float* __restrict__ Wih,   // (NGATE, EMBED)
    const float* __restrict__ Whh,   // (NGATE, HIDDEN)
    const float* __restrict__ bih,   // (NGATE)
    const float* __restrict__ bhh,   // (NGATE)
    float* __restrict__ gates,       // (BATCH, NGATE)
    int t)
{
    __shared__ float As[16][68];     // [k][m], pad 68 keeps b128 aligned, no conflicts
    __shared__ float Ws[16][68];     // [k][n]

    const int tid  = threadIdx.x;
    const int lrow = tid >> 2;          // 0..63 : row loaded by this thread
    const int lk4  = (tid & 3) << 2;    // 0,4,8,12 : k-offset (float4)
    const int tx   = tid & 15;          // n-quad
    const int ty   = tid >> 4;          // m-quad
    const int m0   = blockIdx.y * 64;
    const int n0   = blockIdx.x * 64;

    float acc[4][4] = {};
    float4 av, wv;

    auto prefetch = [&](int k0) {
        const float* Asrc; long astr; const float* Wsrc; int kk;
        if (k0 < EMBED) {
            Asrc = x + (long)t * EMBED; astr = (long)TSTEPS * EMBED;
            Wsrc = Wih; kk = k0;
        } else {
            Asrc = h; astr = HIDDEN;
            Wsrc = Whh; kk = k0 - EMBED;
        }
        const int arow = m0 + lrow;
        av = (arow < BATCH)
               ? *(const float4*)(Asrc + (long)arow * astr + kk + lk4)
               : make_float4(0.f, 0.f, 0.f, 0.f);
        wv = *(const float4*)(Wsrc + (long)(n0 + lrow) * 512 + kk + lk4);
    };

    prefetch(0);
    for (int kt = 0; kt < 64; ++kt) {
        As[lk4 + 0][lrow] = av.x; As[lk4 + 1][lrow] = av.y;
        As[lk4 + 2][lrow] = av.z; As[lk4 + 3][lrow] = av.w;
        Ws[lk4 + 0][lrow] = wv.x; Ws[lk4 + 1][lrow] = wv.y;
        Ws[lk4 + 2][lrow] = wv.z; Ws[lk4 + 3][lrow] = wv.w;
        __syncthreads();
        if (kt < 63) prefetch((kt + 1) * 16);   // hide global latency under compute
        #pragma unroll
        for (int k = 0; k < 16; ++k) {
            const float4 a = *(const float4*)&As[k][ty << 2];
            const float4 w = *(const float4*)&Ws[k][tx << 2];
            const float am[4] = {a.x, a.y, a.z, a.w};
            const float wn[4] = {w.x, w.y, w.z, w.w};
            #pragma unroll
            for (int i = 0; i < 4; ++i)
                #pragma unroll
                for (int j = 0; j < 4; ++j)
                    acc[i][j] = fmaf(am[i], wn[j], acc[i][j]);
        }
        __syncthreads();
    }

    const int nb = n0 + (tx << 2);
    const float4 b1 = *(const float4*)(bih + nb);
    const float4 b2 = *(const float4*)(bhh + nb);
    #pragma unroll
    for (int i = 0; i < 4; ++i) {
        const int m = m0 + (ty << 2) + i;
        if (m < BATCH) {
            float4 o;
            o.x = acc[i][0] + b1.x + b2.x;
            o.y = acc[i][1] + b1.y + b2.y;
            o.z = acc[i][2] + b1.z + b2.z;
            o.w = acc[i][3] + b1.w + b2.w;
            *(float4*)(gates + (long)m * NGATE + nb) = o;
        }
    }
}

__device__ __forceinline__ float sigmoidf_(float v) {
    return 1.f / (1.f + __expf(-v));
}

// ---------------------------------------------------------------------------
// Kernel 2: LSTM cell elementwise update (torch gate order i,f,g,o)
// ---------------------------------------------------------------------------
__global__ __launch_bounds__(256) void cell_kernel(
    const float* __restrict__ gates, float* __restrict__ c, float* __restrict__ h)
{
    const int idx = blockIdx.x * 256 + threadIdx.x;
    if (idx >= BATCH * HIDDEN) return;
    const int b = idx >> 9;
    const int n = idx & 511;
    const float* g = gates + (long)b * NGATE;
    const float ig = sigmoidf_(g[n]);
    const float fg = sigmoidf_(g[n + HIDDEN]);
    const float gg = tanhf(g[n + 2 * HIDDEN]);
    const float og = sigmoidf_(g[n + 3 * HIDDEN]);
    const float cn = fg * c[idx] + ig * gg;
    c[idx] = cn;
    h[idx] = og * tanhf(cn);
}

// ---------------------------------------------------------------------------
// Kernel 3: out[b, t, o] = sigmoid(h[b] . W_fc[o] + b_fc[o])
// One block per batch row; 4 waves x 25 outputs; lanes split K, butterfly sum.
// ---------------------------------------------------------------------------
__global__ __launch_bounds__(256) void fc_kernel(
    const float* __restrict__ h, const float* __restrict__ Wfc,
    const float* __restrict__ bfc, float* __restrict__ out, int t)
{
    const int b    = blockIdx.x;
    const int lane = threadIdx.x & 63;
    const int w    = threadIdx.x >> 6;      // 0..3

    const float* hb = h + (long)b * HIDDEN + lane * 8;
    const float4 h0 = *(const float4*)(hb);
    const float4 h1 = *(const float4*)(hb + 4);
    float* outb = out + (long)b * TSTEPS * OUTF + (long)t * OUTF;

    for (int oi = 0; oi < 25; ++oi) {
        const int o = w * 25 + oi;
        const float* wr = Wfc + (long)o * HIDDEN + lane * 8;
        const float4 w0 = *(const float4*)(wr);
        const float4 w1 = *(const float4*)(wr + 4);
        float p = h0.x * w0.x + h0.y * w0.y + h0.z * w0.z + h0.w * w0.w
                + h1.x * w1.x + h1.y * w1.y + h1.z * w1.z + h1.w * w1.w;
        #pragma unroll
        for (int s = 32; s > 0; s >>= 1) p += __shfl_xor(p, s, 64);
        if (lane == 0) outb[o] = sigmoidf_(p + bfc[o]);
    }
}

extern "C" void kernel_launch(void* const* d_in, const int* in_sizes, int n_in,
                              void* d_out, int out_size, void* d_ws, size_t ws_size,
                              hipStream_t stream) {
    const float* x   = (const float*)d_in[0];   // (500, 1, 256*512)
    const float* Wih = (const float*)d_in[1];   // (2048, 512)
    const float* Whh = (const float*)d_in[2];   // (2048, 512)
    const float* bih = (const float*)d_in[3];   // (2048)
    const float* bhh = (const float*)d_in[4];   // (2048)
    const float* Wfc = (const float*)d_in[5];   // (100, 512)
    const float* bfc = (const float*)d_in[6];   // (100)
    float* out = (float*)d_out;                 // (500, 256, 100) fp32

    float* h     = (float*)d_ws;                // 256000 floats
    float* c     = h + BATCH * HIDDEN;          // 256000 floats
    float* gates = c + BATCH * HIDDEN;          // 1024000 floats (~6.1 MB total)

    // h0 = c0 = 0 (ws is poisoned 0xAA before every call)
    hipMemsetAsync(d_ws, 0, 2 * BATCH * HIDDEN * sizeof(float), stream);

    const dim3 ggrid(NGATE / 64, (BATCH + 63) / 64);   // 32 x 8
    for (int t = 0; t < TSTEPS; ++t) {
        gates_gemm<<<ggrid, 256, 0, stream>>>(x, h, Wih, Whh, bih, bhh, gates, t);
        cell_kernel<<<(BATCH * HIDDEN + 255) / 256, 256, 0, stream>>>(gates, c, h);
        fc_kernel<<<BATCH, 256, 0, stream>>>(h, Wfc, bfc, out, t);
    }
}

// Round 2
// 7236.494 us; speedup vs baseline: 2.5324x; 2.5324x over previous
//
#include <hip/hip_runtime.h>
#include <hip/hip_bf16.h>
#include <math.h>

#define EMBED  512
#define HIDDEN 512
#define NGATE  2048
#define OUTF   100
#define BATCH  500
#define TSTEPS 256
#define XROW   (TSTEPS * EMBED)     // 131072 floats per batch row of x
#define MPAD   512                  // batch padded to 512
#define WHALF  1048576              // frag elems per W matrix: 64nt * 32k16 * 64lane * 8

typedef __bf16 v8bf __attribute__((ext_vector_type(8)));
typedef float  f32x16 __attribute__((ext_vector_type(16)));

__device__ __forceinline__ float sigm_(float v) { return 1.f / (1.f + __expf(-v)); }
__device__ __forceinline__ float tanh_(float v) { return 1.f - 2.f / (__expf(2.f * v) + 1.f); }

// ---------------------------------------------------------------------------
// One-time: convert W_ih / W_hh (fp32, row-major (2048,512)) into bf16 MFMA
// B-fragment order: wf[which][nt][k16][lane][8],
//   row = nt*32 + (lane&31), k = k16*16 + (lane>>5)*8 + slot
// ---------------------------------------------------------------------------
__global__ __launch_bounds__(256) void convert_w(
    const float* __restrict__ Wih, const float* __restrict__ Whh,
    __bf16* __restrict__ wf)
{
    const int idx   = blockIdx.x * 256 + threadIdx.x;   // 0..262143
    const int which = idx >> 17;
    const int s     = idx & 131071;                     // (nt*32 + k16)*64 + lane
    const int lane  = s & 63;
    const int k16   = (s >> 6) & 31;
    const int nt    = s >> 11;
    const int row   = nt * 32 + (lane & 31);
    const int k     = k16 * 16 + ((lane >> 5) << 3);
    const float* W  = which ? Whh : Wih;
    const float* p  = W + (long)row * 512 + k;
    const float4 f0 = *(const float4*)p;
    const float4 f1 = *(const float4*)(p + 4);
    v8bf v;
    v[0] = (__bf16)f0.x; v[1] = (__bf16)f0.y; v[2] = (__bf16)f0.z; v[3] = (__bf16)f0.w;
    v[4] = (__bf16)f1.x; v[5] = (__bf16)f1.y; v[6] = (__bf16)f1.z; v[7] = (__bf16)f1.w;
    *(v8bf*)&wf[(long)which * WHALF + (long)s * 8] = v;
}

// ---------------------------------------------------------------------------
// Fused gates GEMM (bf16 MFMA, K=1024) + LSTM cell update.
// Grid (16 ht, 16 mt), 256 threads = 4 waves; wave w computes gate w's
// 32(M)x32(N) tile with v_mfma_f32_32x32x16_bf16 (16-acc f32).
// A (x then h) staged via LDS in fragment order; B read straight from the
// fragment-ordered bf16 weights (1 KB coalesced per frag).
// ---------------------------------------------------------------------------
__global__ __launch_bounds__(256) void gates_cell(
    const float*  __restrict__ x,
    const __bf16* __restrict__ hbf_in,    // (512,512) bf16, step t-1
    const __bf16* __restrict__ wf,        // frag-ordered weights (ih | hh)
    const float*  __restrict__ bih, const float* __restrict__ bhh,
    float* __restrict__ c,                // (512,512) fp32
    float* __restrict__ h,                // (512,512) fp32 (for FC)
    __bf16* __restrict__ hbf_out,         // (512,512) bf16, step t
    int t)
{
    __shared__ __bf16 Abuf[32 * 64 * 8];      // 32 KB, frag-ordered A
    __shared__ float  Gs[4][32][36];          // gate exchange, pad 36 (16B-aligned rows)

    const int tid  = threadIdx.x;
    const int lane = tid & 63;
    const int w    = tid >> 6;                // gate 0..3 (i,f,g,o)
    const int ht   = blockIdx.x;              // hidden tile 0..15
    const int mt   = blockIdx.y;              // batch tile 0..15

    // ---- stage x tile (k 0..511) fp32 -> bf16, fragment order
    #pragma unroll
    for (int it = 0; it < 8; ++it) {
        const int s   = it * 256 + tid;       // 0..2047 = k16*64 + lane
        const int k16 = s >> 6, ln = s & 63;
        const int r   = ln & 31;
        const int b   = mt * 32 + r;
        const int k   = k16 * 16 + ((ln >> 5) << 3);
        v8bf v;
        if (b < BATCH) {
            const float* p = x + (long)b * XROW + (long)t * EMBED + k;
            const float4 f0 = *(const float4*)p;
            const float4 f1 = *(const float4*)(p + 4);
            v[0] = (__bf16)f0.x; v[1] = (__bf16)f0.y; v[2] = (__bf16)f0.z; v[3] = (__bf16)f0.w;
            v[4] = (__bf16)f1.x; v[5] = (__bf16)f1.y; v[6] = (__bf16)f1.z; v[7] = (__bf16)f1.w;
        } else {
            #pragma unroll
            for (int j = 0; j < 8; ++j) v[j] = (__bf16)0.f;
        }
        *(v8bf*)&Abuf[s * 8] = v;
    }
    __syncthreads();

    f32x16 acc;
    #pragma unroll
    for (int j = 0; j < 16; ++j) acc[j] = 0.f;

    const __bf16* wf_g = wf + (long)((w * 16 + ht) * 32) * 64 * 8;          // W_ih frags
    #pragma unroll 4
    for (int k16 = 0; k16 < 32; ++k16) {
        const v8bf a = *(const v8bf*)&Abuf[(k16 * 64 + lane) * 8];
        const v8bf b = *(const v8bf*)&wf_g[(k16 * 64 + lane) * 8];
        acc = __builtin_amdgcn_mfma_f32_32x32x16_bf16(a, b, acc, 0, 0, 0);
    }
    __syncthreads();

    // ---- stage h tile (k 512..1023) from bf16 h, fragment order
    #pragma unroll
    for (int it = 0; it < 8; ++it) {
        const int s   = it * 256 + tid;
        const int k16 = s >> 6, ln = s & 63;
        const int r   = ln & 31;
        const int k   = k16 * 16 + ((ln >> 5) << 3);
        *(v8bf*)&Abuf[s * 8] = *(const v8bf*)&hbf_in[(long)(mt * 32 + r) * 512 + k];
    }
    __syncthreads();

    const __bf16* wf_h = wf + WHALF + (long)((w * 16 + ht) * 32) * 64 * 8;  // W_hh frags
    #pragma unroll 4
    for (int k16 = 0; k16 < 32; ++k16) {
        const v8bf a = *(const v8bf*)&Abuf[(k16 * 64 + lane) * 8];
        const v8bf b = *(const v8bf*)&wf_h[(k16 * 64 + lane) * 8];
        acc = __builtin_amdgcn_mfma_f32_32x32x16_bf16(a, b, acc, 0, 0, 0);
    }

    // ---- epilogue: bias, exchange gate tiles via LDS
    const int col  = lane & 31;
    const int half = lane >> 5;
    const int gidx = w * 512 + ht * 32 + col;
    const float bias = bih[gidx] + bhh[gidx];
    #pragma unroll
    for (int r = 0; r < 16; ++r) {
        const int m = (r & 3) + 8 * (r >> 2) + 4 * half;   // verified C/D mapping
        Gs[w][m][col] = acc[r] + bias;
    }
    __syncthreads();

    // ---- cell update: thread t -> (m = t>>3, n = (t&7)*4 .. +3)
    {
        const int m  = tid >> 3;
        const int nb = (tid & 7) << 2;
        const int b  = mt * 32 + m;
        if (b < BATCH) {
            const float4 gi = *(const float4*)&Gs[0][m][nb];
            const float4 gf = *(const float4*)&Gs[1][m][nb];
            const float4 gg = *(const float4*)&Gs[2][m][nb];
            const float4 go = *(const float4*)&Gs[3][m][nb];
            const long cix = (long)b * 512 + ht * 32 + nb;
            float4 cv = *(const float4*)&c[cix];
            float4 hv;
            {
                const float i0 = sigm_(gi.x), f0 = sigm_(gf.x), g0 = tanh_(gg.x), o0 = sigm_(go.x);
                cv.x = f0 * cv.x + i0 * g0; hv.x = o0 * tanh_(cv.x);
                const float i1 = sigm_(gi.y), f1 = sigm_(gf.y), g1 = tanh_(gg.y), o1 = sigm_(go.y);
                cv.y = f1 * cv.y + i1 * g1; hv.y = o1 * tanh_(cv.y);
                const float i2 = sigm_(gi.z), f2 = sigm_(gf.z), g2 = tanh_(gg.z), o2 = sigm_(go.z);
                cv.z = f2 * cv.z + i2 * g2; hv.z = o2 * tanh_(cv.z);
                const float i3 = sigm_(gi.w), f3 = sigm_(gf.w), g3 = tanh_(gg.w), o3 = sigm_(go.w);
                cv.w = f3 * cv.w + i3 * g3; hv.w = o3 * tanh_(cv.w);
            }
            *(float4*)&c[cix] = cv;
            *(float4*)&h[cix] = hv;
            union { uint2 u; __bf16 b4[4]; } z;
            z.b4[0] = (__bf16)hv.x; z.b4[1] = (__bf16)hv.y;
            z.b4[2] = (__bf16)hv.z; z.b4[3] = (__bf16)hv.w;
            *(uint2*)&hbf_out[cix] = z.u;
        }
    }
}

// ---------------------------------------------------------------------------
// FC head: out[b,t,o] = sigmoid(h[b] . W_fc[o] + b_fc[o])
// ---------------------------------------------------------------------------
__global__ __launch_bounds__(256) void fc_kernel(
    const float* __restrict__ h, const float* __restrict__ Wfc,
    const float* __restrict__ bfc, float* __restrict__ out, int t)
{
    const int b    = blockIdx.x;
    const int lane = threadIdx.x & 63;
    const int w    = threadIdx.x >> 6;

    const float* hb = h + (long)b * HIDDEN + lane * 8;
    const float4 h0 = *(const float4*)(hb);
    const float4 h1 = *(const float4*)(hb + 4);
    float* outb = out + (long)b * TSTEPS * OUTF + (long)t * OUTF;

    for (int oi = 0; oi < 25; ++oi) {
        const int o = w * 25 + oi;
        const float* wr = Wfc + (long)o * HIDDEN + lane * 8;
        const float4 w0 = *(const float4*)(wr);
        const float4 w1 = *(const float4*)(wr + 4);
        float p = h0.x * w0.x + h0.y * w0.y + h0.z * w0.z + h0.w * w0.w
                + h1.x * w1.x + h1.y * w1.y + h1.z * w1.z + h1.w * w1.w;
        #pragma unroll
        for (int s = 32; s > 0; s >>= 1) p += __shfl_xor(p, s, 64);
        if (lane == 0) outb[o] = sigm_(p + bfc[o]);
    }
}

extern "C" void kernel_launch(void* const* d_in, const int* in_sizes, int n_in,
                              void* d_out, int out_size, void* d_ws, size_t ws_size,
                              hipStream_t stream) {
    const float* x   = (const float*)d_in[0];
    const float* Wih = (const float*)d_in[1];
    const float* Whh = (const float*)d_in[2];
    const float* bih = (const float*)d_in[3];
    const float* bhh = (const float*)d_in[4];
    const float* Wfc = (const float*)d_in[5];
    const float* bfc = (const float*)d_in[6];
    float* out = (float*)d_out;

    // ws layout: [c fp32 1MB][hbfA 0.5MB][hbfB 0.5MB][h fp32 1MB][wf bf16 4MB]
    float*  c    = (float*)d_ws;                       // 512*512
    __bf16* hbfA = (__bf16*)(c + MPAD * HIDDEN);       // 512*512 bf16
    __bf16* hbfB = hbfA + MPAD * HIDDEN;
    float*  h    = (float*)(hbfB + MPAD * HIDDEN);     // 512*512
    __bf16* wf   = (__bf16*)(h + MPAD * HIDDEN);       // 2*WHALF bf16

    // zero c + both bf16 h buffers (contiguous 2 MB)
    hipMemsetAsync(d_ws, 0, (size_t)MPAD * HIDDEN * 4 + (size_t)2 * MPAD * HIDDEN * 2, stream);

    convert_w<<<1024, 256, 0, stream>>>(Wih, Whh, wf);

    const dim3 ggrid(16, 16);
    for (int t = 0; t < TSTEPS; ++t) {
        const __bf16* hin  = (t & 1) ? hbfB : hbfA;
        __bf16*       hout = (t & 1) ? hbfA : hbfB;
        gates_cell<<<ggrid, 256, 0, stream>>>(x, hin, wf, bih, bhh, c, h, hout, t);
        fc_kernel<<<BATCH, 256, 0, stream>>>(h, Wfc, bfc, out, t);
    }
}